// Round 13
// baseline (501.281 us; speedup 1.0000x reference)
//
#include <hip/hip_runtime.h>
#include <stdint.h>

#define VQ_N   131072   // rows = 32*64*64
#define VQ_D   64
#define VQ_K   512
#define NKT    32       // 512/16 k-tiles
#define NBLK   512      // 16 waves/block x 16 rows/wave = 256 rows/block

typedef __attribute__((ext_vector_type(8))) short  short8;   // 8 x bf16 bits
typedef __attribute__((ext_vector_type(4))) float  f32x4;

// ws float-offsets:
#define WS_HN    0        // 512 f:  32 + 0.5*||e_k||^2
#define WS_CBT   512      // 512*64 f: codebook, codeword-major cbt[k][d]
#define WS_FRAG  33280    // bf16x8 ehfrag[32 kt][2 t][64 lane] (eh only, 64 KB)
#define WS_PART  66048    // NBLK f: per-block loss partials

__device__ __forceinline__ unsigned short f2bf(float f) {   // RNE f32->bf16 bits
    unsigned u = __float_as_uint(f);
    u += 0x7FFFu + ((u >> 16) & 1u);
    return (unsigned short)(u >> 16);
}
__device__ __forceinline__ float bf2f(unsigned short h) {
    return __uint_as_float(((unsigned)h) << 16);
}

// Build negated bf16 split of 8 floats: yh = bf16(-x), yl = bf16(-x - yh)
__device__ __forceinline__ void cvt8neg(float4 a, float4 b, short8& hi, short8& lo) {
    float f[8] = {a.x, a.y, a.z, a.w, b.x, b.y, b.z, b.w};
    union { short8 v; unsigned short u[8]; } H, L;
    #pragma unroll
    for (int e = 0; e < 8; ++e) {
        float y = -f[e];
        unsigned short h = f2bf(y);
        H.u[e] = h;
        L.u[e] = f2bf(y - bf2f(h));
    }
    hi = H.v; lo = L.v;
}

// ---------------- prep: codebook norms, fp32 transpose, eh bf16 fragments ---------
__global__ __launch_bounds__(64) void vq_prep(const float* __restrict__ enc,
                                              float* __restrict__ ws) {
    const int k  = blockIdx.x * 64 + threadIdx.x;   // 0..511
    const int kt = k >> 4, c = k & 15;
    float* cbt = ws + WS_CBT;
    unsigned short* frag = (unsigned short*)(ws + WS_FRAG);
    double hs = 0.0;
    for (int d = 0; d < VQ_D; ++d) {
        float v = enc[d * VQ_K + k];               // enc is [D][K]
        cbt[k * VQ_D + d] = v;
        hs += (double)v * (double)v;
        const int t = d >> 5, g = (d >> 3) & 3, e = d & 7;
        const int lane = 16 * g + c;
        frag[(((kt * 2) + t) * 64 + lane) * 8 + e] = f2bf(v);   // eh only
    }
    ws[WS_HN + k] = 32.0f + 0.5f * (float)hs;
}

// ---------------- main: 2-term MFMA screen, packed-u32 per-group top-2,
//                  8-finalist f64 rescreen. eh in LDS (64KB), hn via L1. ----------
__global__ __launch_bounds__(1024) void vq_main(const float* __restrict__ x,
                                                const float* __restrict__ ws,
                                                float* __restrict__ out,
                                                float* __restrict__ partials) {
    const int tid = threadIdx.x;
    const int l   = tid & 63;          // lane
    const int wid = tid >> 6;          // wave in block (0..15)
    const int m   = l & 15;            // x-row (C col), frag spatial idx
    const int g   = l >> 4;            // k-group (d-slice / cand-quad group)
    const int row = (blockIdx.x * 16 + wid) * 16 + m;

    const float*  __restrict__ hnG   = ws + WS_HN;
    const float*  __restrict__ cbt   = ws + WS_CBT;
    const short8* __restrict__ fragG = (const short8*)(ws + WS_FRAG);

    // Stage eh frags (64 KB) into LDS. 64 KB -> 2 blocks/CU.
    __shared__ short8 ehLds[NKT * 2 * 64];
    #pragma unroll
    for (int i = 0; i < 4; ++i) {
        const int idx = i * 1024 + tid;
        ehLds[idx] = fragG[idx];
    }

    // bf16 split of this wave's 16-row set; x reloaded exactly in the epilogue.
    short8 yh0, yl0, yh1, yl1;
    {
        const float* xr = x + (size_t)row * VQ_D;
        float4 a0 = *(const float4*)(xr + 8 * g);
        float4 a1 = *(const float4*)(xr + 8 * g + 4);
        float4 b0 = *(const float4*)(xr + 32 + 8 * g);
        float4 b1 = *(const float4*)(xr + 32 + 8 * g + 4);
        cvt8neg(a0, a1, yh0, yl0);
        cvt8neg(b0, b1, yh1, yl1);
    }

    __syncthreads();   // staging complete

    // Per-(row, group) packed top-2 over this group's 128 candidates.
    // Scores are positive (>= ~19 by the +32 offset) -> float bits order = u32 order.
    // pack = (bits & ~127) | (kt*4 + r): 7-bit local idx, 5e-4 quantization,
    // absorbed by the f64 rescreen; packed ties -> lower idx (first-occurrence).
    unsigned b1p = 0xFFFFFFFFu, b2p = 0xFFFFFFFFu;

    const float* hb = hnG + 4 * g;     // group's hn base (L1-resident broadcast)

    #pragma unroll
    for (int kt = 0; kt < NKT; ++kt) {
        short8 f0 = ehLds[kt * 128 +      l];      // eh d-half0
        short8 f1 = ehLds[kt * 128 + 64 + l];      // eh d-half1
        float4 h4 = *(const float4*)(hb + kt * 16);

        // single 4-MFMA chain: s = (yh+yl).eh + hn
        f32x4 acc = {h4.x, h4.y, h4.z, h4.w};
        acc = __builtin_amdgcn_mfma_f32_16x16x32_bf16(f0, yh0, acc, 0, 0, 0);
        acc = __builtin_amdgcn_mfma_f32_16x16x32_bf16(f1, yh1, acc, 0, 0, 0);
        acc = __builtin_amdgcn_mfma_f32_16x16x32_bf16(f0, yl0, acc, 0, 0, 0);
        acc = __builtin_amdgcn_mfma_f32_16x16x32_bf16(f1, yl1, acc, 0, 0, 0);

        const unsigned p0 = (__float_as_uint(acc[0]) & 0xFFFFFF80u) + (unsigned)(kt * 4 + 0);
        const unsigned p1 = (__float_as_uint(acc[1]) & 0xFFFFFF80u) + (unsigned)(kt * 4 + 1);
        const unsigned p2 = (__float_as_uint(acc[2]) & 0xFFFFFF80u) + (unsigned)(kt * 4 + 2);
        const unsigned p3 = (__float_as_uint(acc[3]) & 0xFFFFFF80u) + (unsigned)(kt * 4 + 3);

        // quad top-2 on u32
        const unsigned m01 = min(p0, p1), M01 = max(p0, p1);
        const unsigned m23 = min(p2, p3), M23 = max(p2, p3);
        const unsigned t1  = min(m01, m23);
        const unsigned t2  = min(max(m01, m23), min(M01, M23));

        // merge into running top-2
        const unsigned nb1 = min(b1p, t1);
        b2p = min(min(max(b1p, t1), b2p), t2);
        b1p = nb1;
    }

    // ---- 8-finalist f64 rescreen (per-group top-2s; no butterfly needed).
    const float* xr = x + (size_t)row * VQ_D;
    float4 xa0 = *(const float4*)(xr + 8 * g);
    float4 xa1 = *(const float4*)(xr + 8 * g + 4);
    float4 xb0 = *(const float4*)(xr + 32 + 8 * g);
    float4 xb1 = *(const float4*)(xr + 32 + 8 * g + 4);
    const float xs[16] = {xa0.x,xa0.y,xa0.z,xa0.w, xa1.x,xa1.y,xa1.z,xa1.w,
                          xb0.x,xb0.y,xb0.z,xb0.w, xb1.x,xb1.y,xb1.z,xb1.w};

    double   best    = 1.0e300;
    unsigned bestIdx = 0xFFFFFFFFu;
    #pragma unroll
    for (int j = 0; j < 8; ++j) {
        const int srcLane = (j & 3) * 16 + m;   // group j&3, this row
        const unsigned pk = (unsigned)__shfl((int)(j < 4 ? b1p : b2p), srcLane, 64);
        const unsigned lo = pk & 127u;          // local idx = kt*4 + r
        const unsigned fi = ((lo >> 2) << 4) + (unsigned)((j & 3) * 4) + (lo & 3u);
        const float* ep = cbt + (size_t)fi * VQ_D;
        float4 p0 = *(const float4*)(ep + 8 * g);
        float4 p1 = *(const float4*)(ep + 8 * g + 4);
        float4 p2 = *(const float4*)(ep + 32 + 8 * g);
        float4 p3 = *(const float4*)(ep + 32 + 8 * g + 4);
        const float qs[16] = {p0.x,p0.y,p0.z,p0.w, p1.x,p1.y,p1.z,p1.w,
                              p2.x,p2.y,p2.z,p2.w, p3.x,p3.y,p3.z,p3.w};
        double dd = 0.0;
        #pragma unroll
        for (int t = 0; t < 16; ++t) {
            double u1 = (double)xs[t] - (double)qs[t];
            dd = fma(u1, u1, dd);
        }
        dd += __shfl_xor(dd, 16, 64);
        dd += __shfl_xor(dd, 32, 64);
        const bool better = (dd < best) || ((dd == best) && (fi < bestIdx));
        best    = better ? dd : best;
        bestIdx = better ? fi : bestIdx;   // lexmin -> numpy first-occurrence
    }

    // ---- gather winner, write output, accumulate loss
    float ls = 0.f;
    {
        const float* ep = cbt + (size_t)bestIdx * VQ_D;
        float4 q0 = *(const float4*)(ep + 8 * g);
        float4 q1o = *(const float4*)(ep + 8 * g + 4);
        float4 q2o = *(const float4*)(ep + 32 + 8 * g);
        float4 q3o = *(const float4*)(ep + 32 + 8 * g + 4);

        float* orow = out + (size_t)row * VQ_D;
        *(float4*)(orow + 8 * g)          = q0;
        *(float4*)(orow + 8 * g + 4)      = q1o;
        *(float4*)(orow + 32 + 8 * g)     = q2o;
        *(float4*)(orow + 32 + 8 * g + 4) = q3o;

        float d;
        d = q0.x  - xa0.x; ls = fmaf(d, d, ls);  d = q0.y  - xa0.y; ls = fmaf(d, d, ls);
        d = q0.z  - xa0.z; ls = fmaf(d, d, ls);  d = q0.w  - xa0.w; ls = fmaf(d, d, ls);
        d = q1o.x - xa1.x; ls = fmaf(d, d, ls);  d = q1o.y - xa1.y; ls = fmaf(d, d, ls);
        d = q1o.z - xa1.z; ls = fmaf(d, d, ls);  d = q1o.w - xa1.w; ls = fmaf(d, d, ls);
        d = q2o.x - xb0.x; ls = fmaf(d, d, ls);  d = q2o.y - xb0.y; ls = fmaf(d, d, ls);
        d = q2o.z - xb0.z; ls = fmaf(d, d, ls);  d = q2o.w - xb0.w; ls = fmaf(d, d, ls);
        d = q3o.x - xb1.x; ls = fmaf(d, d, ls);  d = q3o.y - xb1.y; ls = fmaf(d, d, ls);
        d = q3o.z - xb1.z; ls = fmaf(d, d, ls);  d = q3o.w - xb1.w; ls = fmaf(d, d, ls);
    }

    #pragma unroll
    for (int off = 32; off > 0; off >>= 1) ls += __shfl_xor(ls, off, 64);

    __shared__ float lsw[16];
    if ((tid & 63) == 0) lsw[wid] = ls;
    __syncthreads();
    if (tid == 0) {
        float t = 0.f;
        #pragma unroll
        for (int wv = 0; wv < 16; ++wv) t += lsw[wv];
        partials[blockIdx.x] = t;
    }
}

// ---------------- finalize: deterministic partial-sum + scale ---------------------
__global__ __launch_bounds__(256) void vq_fin(const float* __restrict__ partials,
                                              float* __restrict__ out) {
    const int tid = threadIdx.x;
    float s = 0.f;
    #pragma unroll
    for (int j = 0; j < NBLK / 256; ++j) s += partials[tid + 256 * j];
    #pragma unroll
    for (int off = 32; off > 0; off >>= 1) s += __shfl_xor(s, off, 64);
    __shared__ float w[4];
    if ((tid & 63) == 0) w[tid >> 6] = s;
    __syncthreads();
    if (tid == 0)
        out[(size_t)VQ_N * VQ_D] = 1.25f * (w[0] + w[1] + w[2] + w[3]) / 8388608.0f;
}

extern "C" void kernel_launch(void* const* d_in, const int* in_sizes, int n_in,
                              void* d_out, int out_size, void* d_ws, size_t ws_size,
                              hipStream_t stream) {
    const float* x   = (const float*)d_in[0];   // (32,64,64,64) fp32
    const float* enc = (const float*)d_in[1];   // (64,512) fp32
    float* out = (float*)d_out;                 // 8388608 quantised + 1 loss
    float* ws  = (float*)d_ws;

    vq_prep<<<8, 64, 0, stream>>>(enc, ws);
    vq_main<<<NBLK, 1024, 0, stream>>>(x, ws, out, ws + WS_PART);
    vq_fin<<<1, 256, 0, stream>>>(ws + WS_PART, out);
}

// Round 14
// 76.100 us; speedup vs baseline: 6.5871x; 6.5871x over previous
//
#include <hip/hip_runtime.h>
#include <stdint.h>

#define VQ_N   131072   // rows = 32*64*64
#define VQ_D   64
#define VQ_K   512
#define NKT    32       // 512/16 k-tiles
#define NBLK   1024     // 4 waves/block x 32 rows/wave = 128 rows/block

typedef __attribute__((ext_vector_type(8))) short  short8;   // 8 x bf16 bits
typedef __attribute__((ext_vector_type(4))) float  f32x4;

// ws float-offsets:
#define WS_HN    0        // 512 f:  32 + 0.5*||e_k||^2
#define WS_CBT   512      // 512*64 f: codebook, codeword-major cbt[k][d]
#define WS_FRAG  33280    // bf16x8 ehfrag[32 kt][2 t][64 lane] (eh only, 64 KB)
#define WS_PART  66048    // NBLK f: per-block loss partials

__device__ __forceinline__ unsigned short f2bf(float f) {   // RNE f32->bf16 bits
    unsigned u = __float_as_uint(f);
    u += 0x7FFFu + ((u >> 16) & 1u);
    return (unsigned short)(u >> 16);
}
__device__ __forceinline__ float bf2f(unsigned short h) {
    return __uint_as_float(((unsigned)h) << 16);
}

// Build negated bf16 split of 8 floats: yh = bf16(-x), yl = bf16(-x - yh)
__device__ __forceinline__ void cvt8neg(float4 a, float4 b, short8& hi, short8& lo) {
    float f[8] = {a.x, a.y, a.z, a.w, b.x, b.y, b.z, b.w};
    union { short8 v; unsigned short u[8]; } H, L;
    #pragma unroll
    for (int e = 0; e < 8; ++e) {
        float y = -f[e];
        unsigned short h = f2bf(y);
        H.u[e] = h;
        L.u[e] = f2bf(y - bf2f(h));
    }
    hi = H.v; lo = L.v;
}

// ---------------- prep: codebook norms, fp32 transpose, eh bf16 fragments ---------
__global__ __launch_bounds__(64) void vq_prep(const float* __restrict__ enc,
                                              float* __restrict__ ws) {
    const int k  = blockIdx.x * 64 + threadIdx.x;   // 0..511
    const int kt = k >> 4, c = k & 15;
    float* cbt = ws + WS_CBT;
    unsigned short* frag = (unsigned short*)(ws + WS_FRAG);
    double hs = 0.0;
    for (int d = 0; d < VQ_D; ++d) {
        float v = enc[d * VQ_K + k];               // enc is [D][K]
        cbt[k * VQ_D + d] = v;
        hs += (double)v * (double)v;
        const int t = d >> 5, g = (d >> 3) & 3, e = d & 7;
        const int lane = 16 * g + c;
        frag[(((kt * 2) + t) * 64 + lane) * 8 + e] = f2bf(v);   // eh only
    }
    ws[WS_HN + k] = 32.0f + 0.5f * (float)hs;
}

// ---------------- main: frags streamed from L2 (no LDS staging), 2 sets/wave,
//       2-term MFMA screen, packed-u32 top-2, 8-finalist f64 rescreen -------------
__global__ __launch_bounds__(256) void vq_main(const float* __restrict__ x,
                                               const float* __restrict__ ws,
                                               float* __restrict__ out,
                                               float* __restrict__ partials) {
    const int tid = threadIdx.x;
    const int l   = tid & 63;          // lane
    const int wid = tid >> 6;          // wave in block (0..3)
    const int m   = l & 15;            // x-row (C col), frag spatial idx
    const int g   = l >> 4;            // k-group (d-slice / cand-quad group)
    const int rowbase = (blockIdx.x * 4 + wid) * 32;

    const float*  __restrict__ hnG   = ws + WS_HN;
    const float*  __restrict__ cbt   = ws + WS_CBT;
    const short8* __restrict__ fragG = (const short8*)(ws + WS_FRAG);

    // bf16 split of the two 16-row sets; exact x reloaded in the epilogue.
    short8 yh0[2], yl0[2], yh1[2], yl1[2];
    #pragma unroll
    for (int s = 0; s < 2; ++s) {
        const float* xr = x + (size_t)(rowbase + s * 16 + m) * VQ_D;
        float4 a0 = *(const float4*)(xr + 8 * g);
        float4 a1 = *(const float4*)(xr + 8 * g + 4);
        float4 b0 = *(const float4*)(xr + 32 + 8 * g);
        float4 b1 = *(const float4*)(xr + 32 + 8 * g + 4);
        cvt8neg(a0, a1, yh0[s], yl0[s]);
        cvt8neg(b0, b1, yh1[s], yl1[s]);
    }

    // Per-(row, group) packed top-2 over this group's 128 candidates.
    // Scores positive (+32 offset) -> float bits order-isomorphic to u32.
    // pack = (bits & ~127) | (kt*4+r): 7-bit local idx; quantization ~5e-4,
    // absorbed by the 8-finalist f64 rescreen (validated R12/R13).
    unsigned b1p[2] = {0xFFFFFFFFu, 0xFFFFFFFFu};
    unsigned b2p[2] = {0xFFFFFFFFu, 0xFFFFFFFFu};

    const float* hb = hnG + 4 * g;

    for (int kt = 0; kt < NKT; ++kt) {
        short8 f0 = fragG[kt * 128 +      l];      // eh d-half0 (L2)
        short8 f1 = fragG[kt * 128 + 64 + l];      // eh d-half1 (L2)
        float4 h4 = *(const float4*)(hb + kt * 16);

        #pragma unroll
        for (int s = 0; s < 2; ++s) {
            // single 4-MFMA chain: score = (yh+yl).eh + hn
            f32x4 acc = {h4.x, h4.y, h4.z, h4.w};
            acc = __builtin_amdgcn_mfma_f32_16x16x32_bf16(f0, yh0[s], acc, 0, 0, 0);
            acc = __builtin_amdgcn_mfma_f32_16x16x32_bf16(f1, yh1[s], acc, 0, 0, 0);
            acc = __builtin_amdgcn_mfma_f32_16x16x32_bf16(f0, yl0[s], acc, 0, 0, 0);
            acc = __builtin_amdgcn_mfma_f32_16x16x32_bf16(f1, yl1[s], acc, 0, 0, 0);

            const unsigned p0 = (__float_as_uint(acc[0]) & 0xFFFFFF80u) + (unsigned)(kt * 4 + 0);
            const unsigned p1 = (__float_as_uint(acc[1]) & 0xFFFFFF80u) + (unsigned)(kt * 4 + 1);
            const unsigned p2 = (__float_as_uint(acc[2]) & 0xFFFFFF80u) + (unsigned)(kt * 4 + 2);
            const unsigned p3 = (__float_as_uint(acc[3]) & 0xFFFFFF80u) + (unsigned)(kt * 4 + 3);

            // quad top-2 on u32 (ties -> lower idx = first-occurrence)
            const unsigned m01 = min(p0, p1), M01 = max(p0, p1);
            const unsigned m23 = min(p2, p3), M23 = max(p2, p3);
            const unsigned t1  = min(m01, m23);
            const unsigned t2  = min(max(m01, m23), min(M01, M23));

            // merge into running top-2
            const unsigned nb1 = min(b1p[s], t1);
            b2p[s] = min(min(max(b1p[s], t1), b2p[s]), t2);
            b1p[s] = nb1;
        }
    }

    // ---- per set: 8-finalist f64 rescreen + write + loss (x reloaded exactly)
    float ls = 0.f;
    #pragma unroll
    for (int s = 0; s < 2; ++s) {
        const float* xr = x + (size_t)(rowbase + s * 16 + m) * VQ_D;
        float4 xa0 = *(const float4*)(xr + 8 * g);
        float4 xa1 = *(const float4*)(xr + 8 * g + 4);
        float4 xb0 = *(const float4*)(xr + 32 + 8 * g);
        float4 xb1 = *(const float4*)(xr + 32 + 8 * g + 4);
        const float xs[16] = {xa0.x,xa0.y,xa0.z,xa0.w, xa1.x,xa1.y,xa1.z,xa1.w,
                              xb0.x,xb0.y,xb0.z,xb0.w, xb1.x,xb1.y,xb1.z,xb1.w};

        double   best    = 1.0e300;
        unsigned bestIdx = 0xFFFFFFFFu;
        #pragma unroll
        for (int j = 0; j < 8; ++j) {
            const int srcLane = (j & 3) * 16 + m;   // group j&3, this row
            const unsigned pk = (unsigned)__shfl((int)(j < 4 ? b1p[s] : b2p[s]), srcLane, 64);
            const unsigned lo = pk & 127u;          // local idx = kt*4 + r
            const unsigned fi = ((lo >> 2) << 4) + (unsigned)((j & 3) * 4) + (lo & 3u);
            const float* ep = cbt + (size_t)fi * VQ_D;
            float4 p0 = *(const float4*)(ep + 8 * g);
            float4 p1 = *(const float4*)(ep + 8 * g + 4);
            float4 p2 = *(const float4*)(ep + 32 + 8 * g);
            float4 p3 = *(const float4*)(ep + 32 + 8 * g + 4);
            const float qs[16] = {p0.x,p0.y,p0.z,p0.w, p1.x,p1.y,p1.z,p1.w,
                                  p2.x,p2.y,p2.z,p2.w, p3.x,p3.y,p3.z,p3.w};
            double dd = 0.0;
            #pragma unroll
            for (int t = 0; t < 16; ++t) {
                double u1 = (double)xs[t] - (double)qs[t];
                dd = fma(u1, u1, dd);
            }
            dd += __shfl_xor(dd, 16, 64);
            dd += __shfl_xor(dd, 32, 64);
            const bool better = (dd < best) || ((dd == best) && (fi < bestIdx));
            best    = better ? dd : best;
            bestIdx = better ? fi : bestIdx;   // lexmin -> numpy first-occurrence
        }

        // gather winner, write output, accumulate loss
        const float* ep = cbt + (size_t)bestIdx * VQ_D;
        float4 q0 = *(const float4*)(ep + 8 * g);
        float4 q1o = *(const float4*)(ep + 8 * g + 4);
        float4 q2o = *(const float4*)(ep + 32 + 8 * g);
        float4 q3o = *(const float4*)(ep + 32 + 8 * g + 4);

        float* orow = out + (size_t)(rowbase + s * 16 + m) * VQ_D;
        *(float4*)(orow + 8 * g)          = q0;
        *(float4*)(orow + 8 * g + 4)      = q1o;
        *(float4*)(orow + 32 + 8 * g)     = q2o;
        *(float4*)(orow + 32 + 8 * g + 4) = q3o;

        float d;
        d = q0.x  - xa0.x; ls = fmaf(d, d, ls);  d = q0.y  - xa0.y; ls = fmaf(d, d, ls);
        d = q0.z  - xa0.z; ls = fmaf(d, d, ls);  d = q0.w  - xa0.w; ls = fmaf(d, d, ls);
        d = q1o.x - xa1.x; ls = fmaf(d, d, ls);  d = q1o.y - xa1.y; ls = fmaf(d, d, ls);
        d = q1o.z - xa1.z; ls = fmaf(d, d, ls);  d = q1o.w - xa1.w; ls = fmaf(d, d, ls);
        d = q2o.x - xb0.x; ls = fmaf(d, d, ls);  d = q2o.y - xb0.y; ls = fmaf(d, d, ls);
        d = q2o.z - xb0.z; ls = fmaf(d, d, ls);  d = q2o.w - xb0.w; ls = fmaf(d, d, ls);
        d = q3o.x - xb1.x; ls = fmaf(d, d, ls);  d = q3o.y - xb1.y; ls = fmaf(d, d, ls);
        d = q3o.z - xb1.z; ls = fmaf(d, d, ls);  d = q3o.w - xb1.w; ls = fmaf(d, d, ls);
    }

    #pragma unroll
    for (int off = 32; off > 0; off >>= 1) ls += __shfl_xor(ls, off, 64);

    __shared__ float lsw[4];
    if ((tid & 63) == 0) lsw[wid] = ls;
    __syncthreads();
    if (tid == 0) partials[blockIdx.x] = lsw[0] + lsw[1] + lsw[2] + lsw[3];
}

// ---------------- finalize: deterministic partial-sum + scale ---------------------
__global__ __launch_bounds__(256) void vq_fin(const float* __restrict__ partials,
                                              float* __restrict__ out) {
    const int tid = threadIdx.x;
    float s = 0.f;
    #pragma unroll
    for (int j = 0; j < NBLK / 256; ++j) s += partials[tid + 256 * j];
    #pragma unroll
    for (int off = 32; off > 0; off >>= 1) s += __shfl_xor(s, off, 64);
    __shared__ float w[4];
    if ((tid & 63) == 0) w[tid >> 6] = s;
    __syncthreads();
    if (tid == 0)
        out[(size_t)VQ_N * VQ_D] = 1.25f * (w[0] + w[1] + w[2] + w[3]) / 8388608.0f;
}

extern "C" void kernel_launch(void* const* d_in, const int* in_sizes, int n_in,
                              void* d_out, int out_size, void* d_ws, size_t ws_size,
                              hipStream_t stream) {
    const float* x   = (const float*)d_in[0];   // (32,64,64,64) fp32
    const float* enc = (const float*)d_in[1];   // (64,512) fp32
    float* out = (float*)d_out;                 // 8388608 quantised + 1 loss
    float* ws  = (float*)d_ws;

    vq_prep<<<8, 64, 0, stream>>>(enc, ws);
    vq_main<<<NBLK, 256, 0, stream>>>(x, ws, out, ws + WS_PART);
    vq_fin<<<1, 256, 0, stream>>>(ws + WS_PART, out);
}